// Round 1
// baseline (118.792 us; speedup 1.0000x reference)
//
#include <hip/hip_runtime.h>
#include <hip/hip_bf16.h>

#define BB 1024       // batch
#define DD 256        // embed dim
#define NREL 42       // relations
#define MPAD 48       // padded to 3x16 MFMA tiles
#define APAD 264      // 256 + 8 bf16 pad -> LDS stride 528B, 2-way max conflict (free)

typedef __attribute__((ext_vector_type(8))) short short8_t;
typedef __attribute__((ext_vector_type(4))) short short4_t;
typedef __attribute__((ext_vector_type(4))) float f32x4;

__device__ __forceinline__ unsigned short bf16_of(float f) {
    // round-to-nearest-even f32 -> bf16 (inputs are finite normals)
    unsigned u = __float_as_uint(f);
    return (unsigned short)((u + 0x7FFFu + ((u >> 16) & 1u)) >> 16);
}

// ---------------- K0: convert x to bf16, row-major and transposed ----------------
__global__ __launch_bounds__(256) void cvt_kernel(const float* __restrict__ x,
                                                  unsigned short* __restrict__ xbf,
                                                  unsigned short* __restrict__ xbfT) {
    const int j = blockIdx.x;
    const int d = threadIdx.x;
    const unsigned short h = bf16_of(x[j * DD + d]);
    xbf[j * DD + d] = h;        // [B][D]
    xbfT[d * BB + j] = h;       // [D][B]
}

// ---------------- K1: attn[i,j] = (R[q] . (x_i*x_j)) via per-i GEMM + gather ----
// Workgroup: one i, 256 j's. A_i[k][d] = R[k][d]*x[i][d] staged bf16 in LDS.
// S_i = A_i @ xbf^T  (M=48, N=256, K=256), epilogue picks row q[i,j] per column j.
__global__ __launch_bounds__(256) void attn_kernel(const float* __restrict__ x,
                                                   const int* __restrict__ q,
                                                   const float* __restrict__ R,
                                                   const unsigned short* __restrict__ xbf,
                                                   float* __restrict__ attn) {
    __shared__ unsigned short A[MPAD * APAD];
    const int i = blockIdx.y;
    const int jblock = blockIdx.x * 256;
    const int tid = threadIdx.x;

    // Stage A_i: 48 rows x 256 cols, 8 bf16 per chunk -> 1536 chunks / 256 threads
    for (int c = tid; c < MPAD * (DD / 8); c += 256) {
        const int k = c >> 5;          // DD/8 == 32 chunks per row
        const int d0 = (c & 31) * 8;
        short8_t v;
        if (k < NREL) {
            #pragma unroll
            for (int e = 0; e < 8; ++e)
                v[e] = (short)bf16_of(R[k * DD + d0 + e] * x[i * DD + d0 + e]);
        } else {
            v = (short8_t)0;
        }
        *reinterpret_cast<short8_t*>(&A[k * APAD + d0]) = v;
    }
    __syncthreads();

    const int wave = tid >> 6;
    const int lane = tid & 63;
    const int lcol = lane & 15;        // A-row / B-col / C-col index
    const int lk8  = (lane >> 4) * 8;  // k-offset within K=32 step
    const int j0w  = jblock + wave * 64;

    f32x4 acc[3][4];
    #pragma unroll
    for (int mt = 0; mt < 3; ++mt)
        #pragma unroll
        for (int nt = 0; nt < 4; ++nt)
            acc[mt][nt] = (f32x4)0.0f;

    #pragma unroll
    for (int ks = 0; ks < 8; ++ks) {
        short8_t a[3];
        #pragma unroll
        for (int mt = 0; mt < 3; ++mt)
            a[mt] = *reinterpret_cast<const short8_t*>(
                &A[(mt * 16 + lcol) * APAD + ks * 32 + lk8]);
        #pragma unroll
        for (int nt = 0; nt < 4; ++nt) {
            const short8_t b = *reinterpret_cast<const short8_t*>(
                &xbf[(j0w + nt * 16 + lcol) * DD + ks * 32 + lk8]);
            #pragma unroll
            for (int mt = 0; mt < 3; ++mt)
                acc[mt][nt] = __builtin_amdgcn_mfma_f32_16x16x32_bf16(a[mt], b, acc[mt][nt], 0, 0, 0);
        }
    }

    // Epilogue: C/D layout col=lane&15, row=(lane>>4)*4+r. Select row == q[i,j].
    const int rbase = (lane >> 4) * 4;
    #pragma unroll
    for (int nt = 0; nt < 4; ++nt) {
        const int j = j0w + nt * 16 + lcol;
        const int qv = q[i * BB + j];
        #pragma unroll
        for (int mt = 0; mt < 3; ++mt)
            #pragma unroll
            for (int r = 0; r < 4; ++r)
                if (mt * 16 + rbase + r == qv)
                    attn[i * BB + j] = acc[mt][nt][r];
    }
}

// ---------------- K2: row softmax -> P (bf16), rowsum (f32) ---------------------
__global__ __launch_bounds__(256) void softmax_kernel(const float* __restrict__ attn,
                                                      unsigned short* __restrict__ P,
                                                      float* __restrict__ rowsum) {
    const int i = blockIdx.x;
    const int tid = threadIdx.x;
    const int wave = tid >> 6, lane = tid & 63;
    const f32x4 a = *reinterpret_cast<const f32x4*>(&attn[i * BB + tid * 4]);

    float m = fmaxf(fmaxf(a[0], a[1]), fmaxf(a[2], a[3]));
    #pragma unroll
    for (int off = 1; off < 64; off <<= 1) m = fmaxf(m, __shfl_xor(m, off));

    __shared__ float red[4];
    if (lane == 0) red[wave] = m;
    __syncthreads();
    m = fmaxf(fmaxf(red[0], red[1]), fmaxf(red[2], red[3]));

    const float e0 = __expf(a[0] - m), e1 = __expf(a[1] - m);
    const float e2 = __expf(a[2] - m), e3 = __expf(a[3] - m);
    float s = (e0 + e1) + (e2 + e3);
    #pragma unroll
    for (int off = 1; off < 64; off <<= 1) s += __shfl_xor(s, off);
    __syncthreads();
    if (lane == 0) red[wave] = s;
    __syncthreads();
    s = (red[0] + red[1]) + (red[2] + red[3]);

    short4_t p;
    p[0] = (short)bf16_of(e0); p[1] = (short)bf16_of(e1);
    p[2] = (short)bf16_of(e2); p[3] = (short)bf16_of(e3);
    *reinterpret_cast<short4_t*>(&P[i * BB + tid * 4]) = p;
    if (tid == 0) rowsum[i] = s;
}

// ---------------- K3: out[i,d] = (1/rowsum[i]) * sum_j P[i,j] * x[j,d] ----------
// MFMA GEMM: M=1024 (i), N=256 (d), K=1024 (j). A=P [i][j], B=xbfT [d][j].
// Workgroup: 4 waves, 64 i x 64 d tile; wave owns 16 i x 64 d.
__global__ __launch_bounds__(256) void out_kernel(const unsigned short* __restrict__ P,
                                                  const unsigned short* __restrict__ xbfT,
                                                  const float* __restrict__ rowsum,
                                                  float* __restrict__ out) {
    const int tid = threadIdx.x;
    const int wave = tid >> 6, lane = tid & 63;
    const int lcol = lane & 15;
    const int lk8  = (lane >> 4) * 8;
    const int i0 = blockIdx.y * 64 + wave * 16;
    const int d0 = blockIdx.x * 64;

    f32x4 acc[4];
    #pragma unroll
    for (int nt = 0; nt < 4; ++nt) acc[nt] = (f32x4)0.0f;

    #pragma unroll 4
    for (int ks = 0; ks < 32; ++ks) {
        const short8_t a = *reinterpret_cast<const short8_t*>(
            &P[(i0 + lcol) * BB + ks * 32 + lk8]);
        #pragma unroll
        for (int nt = 0; nt < 4; ++nt) {
            const short8_t b = *reinterpret_cast<const short8_t*>(
                &xbfT[(d0 + nt * 16 + lcol) * BB + ks * 32 + lk8]);
            acc[nt] = __builtin_amdgcn_mfma_f32_16x16x32_bf16(a, b, acc[nt], 0, 0, 0);
        }
    }

    const int rbase = (lane >> 4) * 4;
    #pragma unroll
    for (int r = 0; r < 4; ++r) {
        const int irow = i0 + rbase + r;
        const float inv = 1.0f / rowsum[irow];
        #pragma unroll
        for (int nt = 0; nt < 4; ++nt)
            out[irow * DD + d0 + nt * 16 + lcol] = acc[nt][r] * inv;
    }
}

// ---------------- launch --------------------------------------------------------
extern "C" void kernel_launch(void* const* d_in, const int* in_sizes, int n_in,
                              void* d_out, int out_size, void* d_ws, size_t ws_size,
                              hipStream_t stream) {
    (void)in_sizes; (void)n_in; (void)out_size; (void)ws_size;
    const float* x = (const float*)d_in[0];
    // d_in[1] = x_mask (unused), d_in[3] = f (unused)
    const int* q = (const int*)d_in[2];
    const float* R = (const float*)d_in[4];
    float* out = (float*)d_out;

    char* ws = (char*)d_ws;
    unsigned short* xbf    = (unsigned short*)(ws);                  // 512 KB
    unsigned short* xbfT   = (unsigned short*)(ws + (512u << 10));   // 512 KB
    float*          attn   = (float*)(ws + (1024u << 10));           // 4 MB
    unsigned short* P      = (unsigned short*)(ws + (5120u << 10));  // 2 MB
    float*          rowsum = (float*)(ws + (7168u << 10));           // 4 KB

    cvt_kernel<<<dim3(BB), 256, 0, stream>>>(x, xbf, xbfT);
    attn_kernel<<<dim3(4, BB), 256, 0, stream>>>(x, q, R, xbf, attn);
    softmax_kernel<<<dim3(BB), 256, 0, stream>>>(attn, P, rowsum);
    out_kernel<<<dim3(4, 16), 256, 0, stream>>>(P, xbfT, rowsum, out);
}

// Round 2
// 97.954 us; speedup vs baseline: 1.2127x; 1.2127x over previous
//
#include <hip/hip_runtime.h>
#include <hip/hip_bf16.h>

#define BB 1024       // batch
#define DD 256        // embed dim
#define NREL 42       // relations
#define MPAD 48       // padded to 3x16 MFMA tiles
#define APAD 264      // 256 + 8 bf16 pad -> LDS stride 528B, 2-way max conflict (free)

typedef __attribute__((ext_vector_type(8))) short short8_t;
typedef __attribute__((ext_vector_type(4))) short short4_t;
typedef __attribute__((ext_vector_type(4))) float f32x4;
typedef __attribute__((ext_vector_type(4))) int   i32x4;

__device__ __forceinline__ unsigned short bf16_of(float f) {
    // round-to-nearest-even f32 -> bf16 (inputs are finite normals)
    unsigned u = __float_as_uint(f);
    return (unsigned short)((u + 0x7FFFu + ((u >> 16) & 1u)) >> 16);
}

// ---------------- K0: x -> bf16 row-major + LDS-tiled transpose -----------------
// grid (16, 4): 64x64 tiles of [B][D].
__global__ __launch_bounds__(256) void cvt_kernel(const float* __restrict__ x,
                                                  unsigned short* __restrict__ xbf,
                                                  unsigned short* __restrict__ xbfT) {
    __shared__ unsigned short t[64][72];
    const int bj = blockIdx.x * 64;
    const int bd = blockIdx.y * 64;
    const int tr = threadIdx.x >> 4;   // 0..15
    const int tc = threadIdx.x & 15;   // 0..15

    #pragma unroll
    for (int rr = 0; rr < 4; ++rr) {
        const int jl = rr * 16 + tr;
        const f32x4 v = *reinterpret_cast<const f32x4*>(&x[(bj + jl) * DD + bd + tc * 4]);
        short4_t h;
        #pragma unroll
        for (int e = 0; e < 4; ++e) h[e] = (short)bf16_of(v[e]);
        *reinterpret_cast<short4_t*>(&xbf[(bj + jl) * DD + bd + tc * 4]) = h;
        *reinterpret_cast<short4_t*>(&t[jl][tc * 4]) = h;
    }
    __syncthreads();
    #pragma unroll
    for (int rr = 0; rr < 4; ++rr) {
        const int dl = rr * 16 + tr;
        short4_t h;
        #pragma unroll
        for (int e = 0; e < 4; ++e) h[e] = (short)t[tc * 4 + e][dl];
        *reinterpret_cast<short4_t*>(&xbfT[(bd + dl) * BB + bj + tc * 4]) = h;
    }
}

// ---------------- K1 (fused): logits GEMM + gather + softmax -> P, rowsum -------
// One block per row i. A_i[k][d] = R[k][d]*x[i][d] staged once (bf16, LDS).
// Loop 4 j-tiles of 256: S = A_i @ xbf^T (M=48,N=256,K=256) via 16x16x32 MFMA,
// epilogue selects row q[i,j] per column j into s_attn. Then block softmax.
__global__ __launch_bounds__(256) void attn_kernel(const float* __restrict__ x,
                                                   const int* __restrict__ q,
                                                   const float* __restrict__ R,
                                                   const unsigned short* __restrict__ xbf,
                                                   unsigned short* __restrict__ P,
                                                   float* __restrict__ rowsum) {
    __shared__ unsigned short A[MPAD * APAD];   // 25344 B
    __shared__ float s_attn[BB];                // 4096 B
    __shared__ int   s_q[BB];                   // 4096 B
    __shared__ float red[4];

    const int i = blockIdx.x;
    const int tid = threadIdx.x;

    // q row -> LDS (one int4 per thread)
    *reinterpret_cast<i32x4*>(&s_q[tid * 4]) =
        *reinterpret_cast<const i32x4*>(&q[i * BB + tid * 4]);

    // Stage A_i: 48 rows x 256 cols, 8 bf16 per chunk
    for (int c = tid; c < MPAD * (DD / 8); c += 256) {
        const int k = c >> 5;          // 32 chunks per row
        const int d0 = (c & 31) * 8;
        short8_t v;
        if (k < NREL) {
            const f32x4 r0 = *reinterpret_cast<const f32x4*>(&R[k * DD + d0]);
            const f32x4 r1 = *reinterpret_cast<const f32x4*>(&R[k * DD + d0 + 4]);
            const f32x4 x0 = *reinterpret_cast<const f32x4*>(&x[i * DD + d0]);
            const f32x4 x1 = *reinterpret_cast<const f32x4*>(&x[i * DD + d0 + 4]);
            #pragma unroll
            for (int e = 0; e < 4; ++e) {
                v[e]     = (short)bf16_of(r0[e] * x0[e]);
                v[e + 4] = (short)bf16_of(r1[e] * x1[e]);
            }
        } else {
            v = (short8_t)0;
        }
        *reinterpret_cast<short8_t*>(&A[k * APAD + d0]) = v;
    }
    __syncthreads();

    const int wave = tid >> 6;
    const int lane = tid & 63;
    const int lcol  = lane & 15;        // A-row / B-col / C-col index
    const int lk8   = (lane >> 4) * 8;  // k-offset within K=32 step
    const int rbase = (lane >> 4) * 4;  // C/D row base

    for (int jt = 0; jt < 4; ++jt) {
        const int j0w = jt * 256 + wave * 64;

        f32x4 acc[3][4];
        #pragma unroll
        for (int mt = 0; mt < 3; ++mt)
            #pragma unroll
            for (int nt = 0; nt < 4; ++nt)
                acc[mt][nt] = (f32x4)0.0f;

        #pragma unroll
        for (int ks = 0; ks < 8; ++ks) {
            short8_t a[3];
            #pragma unroll
            for (int mt = 0; mt < 3; ++mt)
                a[mt] = *reinterpret_cast<const short8_t*>(
                    &A[(mt * 16 + lcol) * APAD + ks * 32 + lk8]);
            #pragma unroll
            for (int nt = 0; nt < 4; ++nt) {
                const short8_t b = *reinterpret_cast<const short8_t*>(
                    &xbf[(j0w + nt * 16 + lcol) * DD + ks * 32 + lk8]);
                #pragma unroll
                for (int mt = 0; mt < 3; ++mt)
                    acc[mt][nt] = __builtin_amdgcn_mfma_f32_16x16x32_bf16(a[mt], b, acc[mt][nt], 0, 0, 0);
            }
        }

        // Select row q[i,j] per column j into the LDS logit row.
        #pragma unroll
        for (int nt = 0; nt < 4; ++nt) {
            const int j = j0w + nt * 16 + lcol;
            const int qv = s_q[j];
            #pragma unroll
            for (int mt = 0; mt < 3; ++mt)
                #pragma unroll
                for (int r = 0; r < 4; ++r)
                    if (mt * 16 + rbase + r == qv)
                        s_attn[j] = acc[mt][nt][r];
        }
    }
    __syncthreads();

    // Block-wide softmax over s_attn[0..1023]; write P row (bf16) + rowsum.
    const f32x4 a4 = *reinterpret_cast<const f32x4*>(&s_attn[tid * 4]);
    float m = fmaxf(fmaxf(a4[0], a4[1]), fmaxf(a4[2], a4[3]));
    #pragma unroll
    for (int off = 1; off < 64; off <<= 1) m = fmaxf(m, __shfl_xor(m, off));
    if (lane == 0) red[wave] = m;
    __syncthreads();
    m = fmaxf(fmaxf(red[0], red[1]), fmaxf(red[2], red[3]));

    const float e0 = __expf(a4[0] - m), e1 = __expf(a4[1] - m);
    const float e2 = __expf(a4[2] - m), e3 = __expf(a4[3] - m);
    float s = (e0 + e1) + (e2 + e3);
    #pragma unroll
    for (int off = 1; off < 64; off <<= 1) s += __shfl_xor(s, off);
    __syncthreads();                 // red[] reuse: all reads of max done
    if (lane == 0) red[wave] = s;
    __syncthreads();
    s = (red[0] + red[1]) + (red[2] + red[3]);

    short4_t p;
    p[0] = (short)bf16_of(e0); p[1] = (short)bf16_of(e1);
    p[2] = (short)bf16_of(e2); p[3] = (short)bf16_of(e3);
    *reinterpret_cast<short4_t*>(&P[i * BB + tid * 4]) = p;
    if (tid == 0) rowsum[i] = s;
}

// ---------------- K3a: partial out GEMM, split-K over z --------------------------
// part[z][i][d] = sum_{j in half z} P[i,j] * x[j,d]
__global__ __launch_bounds__(256) void out_partial(const unsigned short* __restrict__ P,
                                                   const unsigned short* __restrict__ xbfT,
                                                   float* __restrict__ part) {
    const int tid = threadIdx.x;
    const int wave = tid >> 6, lane = tid & 63;
    const int lcol = lane & 15;
    const int lk8  = (lane >> 4) * 8;
    const int i0 = blockIdx.y * 64 + wave * 16;
    const int d0 = blockIdx.x * 64;
    const int k0 = blockIdx.z * 512;

    f32x4 acc[4];
    #pragma unroll
    for (int nt = 0; nt < 4; ++nt) acc[nt] = (f32x4)0.0f;

    #pragma unroll 4
    for (int ks = 0; ks < 16; ++ks) {
        const short8_t a = *reinterpret_cast<const short8_t*>(
            &P[(i0 + lcol) * BB + k0 + ks * 32 + lk8]);
        #pragma unroll
        for (int nt = 0; nt < 4; ++nt) {
            const short8_t b = *reinterpret_cast<const short8_t*>(
                &xbfT[(d0 + nt * 16 + lcol) * BB + k0 + ks * 32 + lk8]);
            acc[nt] = __builtin_amdgcn_mfma_f32_16x16x32_bf16(a, b, acc[nt], 0, 0, 0);
        }
    }

    const int rbase = (lane >> 4) * 4;
    float* pz = part + (size_t)blockIdx.z * BB * DD;
    #pragma unroll
    for (int r = 0; r < 4; ++r)
        #pragma unroll
        for (int nt = 0; nt < 4; ++nt)
            pz[(i0 + rbase + r) * DD + d0 + nt * 16 + lcol] = acc[nt][r];
}

// ---------------- K3b: out = (part0 + part1) / rowsum ---------------------------
__global__ __launch_bounds__(256) void out_reduce(const float* __restrict__ part,
                                                  const float* __restrict__ rowsum,
                                                  float* __restrict__ out) {
    const int i = blockIdx.x;
    const int d = threadIdx.x;
    const float inv = 1.0f / rowsum[i];
    out[i * DD + d] = (part[i * DD + d] + part[BB * DD + i * DD + d]) * inv;
}

// ---------------- launch --------------------------------------------------------
extern "C" void kernel_launch(void* const* d_in, const int* in_sizes, int n_in,
                              void* d_out, int out_size, void* d_ws, size_t ws_size,
                              hipStream_t stream) {
    (void)in_sizes; (void)n_in; (void)out_size; (void)ws_size;
    const float* x = (const float*)d_in[0];
    // d_in[1] = x_mask (unused), d_in[3] = f (unused)
    const int* q = (const int*)d_in[2];
    const float* R = (const float*)d_in[4];
    float* out = (float*)d_out;

    char* ws = (char*)d_ws;
    unsigned short* xbf    = (unsigned short*)(ws);                  // 512 KB
    unsigned short* xbfT   = (unsigned short*)(ws + (512u << 10));   // 512 KB
    unsigned short* P      = (unsigned short*)(ws + (1024u << 10));  // 2 MB
    float*          rowsum = (float*)(ws + (3072u << 10));           // 4 KB
    float*          part   = (float*)(ws + (3136u << 10));           // 2 MB (z=2)

    cvt_kernel<<<dim3(16, 4), 256, 0, stream>>>(x, xbf, xbfT);
    attn_kernel<<<dim3(BB), 256, 0, stream>>>(x, q, R, xbf, P, rowsum);
    out_partial<<<dim3(4, 16, 2), 256, 0, stream>>>(P, xbfT, part);
    out_reduce<<<dim3(BB), 256, 0, stream>>>(part, rowsum, out);
}

// Round 3
// 77.722 us; speedup vs baseline: 1.5284x; 1.2603x over previous
//
#include <hip/hip_runtime.h>
#include <hip/hip_bf16.h>

#define BB 1024
#define DD 256
#define NREL 42

typedef __attribute__((ext_vector_type(8))) short short8_t;
typedef __attribute__((ext_vector_type(4))) short short4_t;
typedef __attribute__((ext_vector_type(4))) float f32x4;
typedef __attribute__((ext_vector_type(4))) int   i32x4;

__device__ __forceinline__ unsigned short bf16_of(float f) {
    // round-to-nearest-even f32 -> bf16 (inputs are finite normals)
    unsigned u = __float_as_uint(f);
    return (unsigned short)((u + 0x7FFFu + ((u >> 16) & 1u)) >> 16);
}

__device__ __forceinline__ void gload_lds16(const unsigned short* g, unsigned short* l) {
    __builtin_amdgcn_global_load_lds(
        (const __attribute__((address_space(1))) unsigned int*)g,
        (__attribute__((address_space(3))) unsigned int*)l, 16, 0, 0);
}

// ---------------- K0: x -> bf16 row-major + LDS-tiled transpose -----------------
__global__ __launch_bounds__(256) void cvt_kernel(const float* __restrict__ x,
                                                  unsigned short* __restrict__ xbf,
                                                  unsigned short* __restrict__ xbfT) {
    __shared__ unsigned short t[64][72];
    const int bj = blockIdx.x * 64;
    const int bd = blockIdx.y * 64;
    const int tr = threadIdx.x >> 4;
    const int tc = threadIdx.x & 15;

    #pragma unroll
    for (int rr = 0; rr < 4; ++rr) {
        const int jl = rr * 16 + tr;
        const f32x4 v = *reinterpret_cast<const f32x4*>(&x[(bj + jl) * DD + bd + tc * 4]);
        short4_t h;
        #pragma unroll
        for (int e = 0; e < 4; ++e) h[e] = (short)bf16_of(v[e]);
        *reinterpret_cast<short4_t*>(&xbf[(bj + jl) * DD + bd + tc * 4]) = h;
        *reinterpret_cast<short4_t*>(&t[jl][tc * 4]) = h;
    }
    __syncthreads();
    #pragma unroll
    for (int rr = 0; rr < 4; ++rr) {
        const int dl = rr * 16 + tr;
        short4_t h;
        #pragma unroll
        for (int e = 0; e < 4; ++e) h[e] = (short)t[tc * 4 + e][dl];
        *reinterpret_cast<short4_t*>(&xbfT[(bd + dl) * BB + bj + tc * 4]) = h;
    }
}

// ---------------- K1 (fused): logits GEMM + gather + softmax -> normalized P ----
// Block = 2 waves = 2 rows i. A_i (48x256 bf16) held in VGPRs per wave.
// B = xbf j-tiles (32 x 256) staged LDS via global_load_lds, double-buffered,
// XOR-swizzled (byte ^= (row&7)<<4) via pre-swizzled global source + swizzled read.
__global__ __launch_bounds__(128) void attn_kernel(const float* __restrict__ x,
                                                   const int* __restrict__ q,
                                                   const float* __restrict__ R,
                                                   const unsigned short* __restrict__ xbf,
                                                   unsigned short* __restrict__ P) {
    __shared__ unsigned short Bt[2][8192];      // 2 x (32 j x 256 d) bf16, swizzled
    __shared__ float s_attn[2][BB];             // per-wave logit row
    __shared__ unsigned short s_qs[2][BB];      // per-wave q row (values < 42)

    const int tid  = threadIdx.x;
    const int wave = tid >> 6;
    const int lane = tid & 63;
    const int lcol = lane & 15;
    const int g    = lane >> 4;
    const int lk8  = g * 8;
    const int rbase = g * 4;
    const int l5 = lane >> 5, l31 = lane & 31;
    const int i = blockIdx.x * 2 + wave;

    // --- stage tile 0 (async, fire-and-forget) ---
    #pragma unroll
    for (int s = 0; s < 8; ++s) {
        const int c = wave * 8 + s;                 // 1KB chunk = 2 rows
        const int row = c * 2 + l5;
        const int scol = ((l31 * 16) ^ ((row & 7) << 4)) >> 1;  // ushort idx
        gload_lds16(&xbf[row * DD + scol], &Bt[0][c * 512]);
    }

    // --- q row -> LDS (u16) ---
    #pragma unroll
    for (int kk = 0; kk < 4; ++kk) {
        const i32x4 qv = *reinterpret_cast<const i32x4*>(&q[i * BB + kk * 256 + lane * 4]);
        short4_t qs;
        qs[0] = (short)qv[0]; qs[1] = (short)qv[1];
        qs[2] = (short)qv[2]; qs[3] = (short)qv[3];
        *reinterpret_cast<short4_t*>(&s_qs[wave][kk * 256 + lane * 4]) = qs;
    }

    // --- A_i fragments in registers: afrag[mt*8+ks][e] = bf16(R[k][d]*x[i][d]) ---
    short8_t afrag[24];
    #pragma unroll
    for (int ks = 0; ks < 8; ++ks) {
        const int d0 = ks * 32 + lk8;
        const f32x4 x0 = *reinterpret_cast<const f32x4*>(&x[i * DD + d0]);
        const f32x4 x1 = *reinterpret_cast<const f32x4*>(&x[i * DD + d0 + 4]);
        #pragma unroll
        for (int mt = 0; mt < 3; ++mt) {
            const int k = mt * 16 + lcol;
            short8_t v = (short8_t)0;
            if (k < NREL) {
                const f32x4 r0 = *reinterpret_cast<const f32x4*>(&R[k * DD + d0]);
                const f32x4 r1 = *reinterpret_cast<const f32x4*>(&R[k * DD + d0 + 4]);
                #pragma unroll
                for (int e = 0; e < 4; ++e) {
                    v[e]     = (short)bf16_of(r0[e] * x0[e]);
                    v[e + 4] = (short)bf16_of(r1[e] * x1[e]);
                }
            }
            afrag[mt * 8 + ks] = v;
        }
    }

    asm volatile("s_waitcnt vmcnt(0)" ::: "memory");
    __syncthreads();

    const int gsw = (g * 16) ^ ((lcol & 7) << 4);   // swizzled column byte base

    for (int t = 0; t < 32; ++t) {
        // issue next-tile staging BEFORE compute (latency hides under MFMA)
        if (t < 31) {
            unsigned short* nxt = Bt[(t + 1) & 1];
            const int j0n = (t + 1) * 32;
            #pragma unroll
            for (int s = 0; s < 8; ++s) {
                const int c = wave * 8 + s;
                const int row = c * 2 + l5;
                const int scol = ((l31 * 16) ^ ((row & 7) << 4)) >> 1;
                gload_lds16(&xbf[(j0n + row) * DD + scol], &nxt[c * 512]);
            }
        }

        const char* cur = (const char*)Bt[t & 1];
        f32x4 acc[3][2];
        #pragma unroll
        for (int mt = 0; mt < 3; ++mt) {
            acc[mt][0] = (f32x4)0.0f; acc[mt][1] = (f32x4)0.0f;
        }

        #pragma unroll
        for (int ks = 0; ks < 8; ++ks) {
            #pragma unroll
            for (int nt = 0; nt < 2; ++nt) {
                const int off = (nt * 16 + lcol) * 512 + ((ks * 64) ^ gsw);
                const short8_t b = *reinterpret_cast<const short8_t*>(cur + off);
                #pragma unroll
                for (int mt = 0; mt < 3; ++mt)
                    acc[mt][nt] = __builtin_amdgcn_mfma_f32_16x16x32_bf16(
                        afrag[mt * 8 + ks], b, acc[mt][nt], 0, 0, 0);
            }
        }

        // Epilogue: pick row q[i,j] of S per column j into the wave's logit row.
        const int j0 = t * 32;
        #pragma unroll
        for (int nt = 0; nt < 2; ++nt) {
            const int jl = j0 + nt * 16 + lcol;
            const int qv = (int)s_qs[wave][jl];
            #pragma unroll
            for (int mt = 0; mt < 3; ++mt)
                #pragma unroll
                for (int r = 0; r < 4; ++r)
                    if (mt * 16 + rbase + r == qv)
                        s_attn[wave][jl] = acc[mt][nt][r];
        }

        asm volatile("s_waitcnt vmcnt(0)" ::: "memory");
        __syncthreads();
    }

    // --- per-wave softmax over s_attn[wave][0..1023]; write normalized P (bf16) --
    const float* sa = s_attn[wave];
    f32x4 v4[4];
    #pragma unroll
    for (int kk = 0; kk < 4; ++kk)
        v4[kk] = *reinterpret_cast<const f32x4*>(&sa[kk * 256 + lane * 4]);

    float m = -1e30f;
    #pragma unroll
    for (int kk = 0; kk < 4; ++kk)
        m = fmaxf(m, fmaxf(fmaxf(v4[kk][0], v4[kk][1]), fmaxf(v4[kk][2], v4[kk][3])));
    #pragma unroll
    for (int off = 1; off < 64; off <<= 1) m = fmaxf(m, __shfl_xor(m, off));

    float e[16];
    float ssum = 0.f;
    #pragma unroll
    for (int kk = 0; kk < 4; ++kk)
        #pragma unroll
        for (int ee = 0; ee < 4; ++ee) {
            const float t2 = __expf(v4[kk][ee] - m);
            e[kk * 4 + ee] = t2;
            ssum += t2;
        }
    #pragma unroll
    for (int off = 1; off < 64; off <<= 1) ssum += __shfl_xor(ssum, off);
    const float inv = 1.0f / ssum;

    #pragma unroll
    for (int kk = 0; kk < 4; ++kk) {
        short4_t p;
        #pragma unroll
        for (int ee = 0; ee < 4; ++ee) p[ee] = (short)bf16_of(e[kk * 4 + ee] * inv);
        *reinterpret_cast<short4_t*>(&P[i * BB + kk * 256 + lane * 4]) = p;
    }
}

// ---------------- K3a: partial out GEMM, split-K z=4 -----------------------------
// part[z][i][d] = sum_{j in quarter z} P[i,j] * x[j,d]
__global__ __launch_bounds__(256) void out_partial(const unsigned short* __restrict__ P,
                                                   const unsigned short* __restrict__ xbfT,
                                                   float* __restrict__ part) {
    const int tid = threadIdx.x;
    const int wave = tid >> 6, lane = tid & 63;
    const int lcol = lane & 15;
    const int lk8  = (lane >> 4) * 8;
    const int i0 = blockIdx.y * 64 + wave * 16;
    const int d0 = blockIdx.x * 64;
    const int k0 = blockIdx.z * 256;

    f32x4 acc[4];
    #pragma unroll
    for (int nt = 0; nt < 4; ++nt) acc[nt] = (f32x4)0.0f;

    #pragma unroll
    for (int ks = 0; ks < 8; ++ks) {
        const short8_t a = *reinterpret_cast<const short8_t*>(
            &P[(i0 + lcol) * BB + k0 + ks * 32 + lk8]);
        #pragma unroll
        for (int nt = 0; nt < 4; ++nt) {
            const short8_t b = *reinterpret_cast<const short8_t*>(
                &xbfT[(d0 + nt * 16 + lcol) * BB + k0 + ks * 32 + lk8]);
            acc[nt] = __builtin_amdgcn_mfma_f32_16x16x32_bf16(a, b, acc[nt], 0, 0, 0);
        }
    }

    const int rbase = (lane >> 4) * 4;
    float* pz = part + (size_t)blockIdx.z * BB * DD;
    #pragma unroll
    for (int r = 0; r < 4; ++r)
        #pragma unroll
        for (int nt = 0; nt < 4; ++nt)
            pz[(i0 + rbase + r) * DD + d0 + nt * 16 + lcol] = acc[nt][r];
}

// ---------------- K3b: out = sum_z part[z] (P already normalized) ---------------
__global__ __launch_bounds__(256) void out_reduce(const float* __restrict__ part,
                                                  float* __restrict__ out) {
    const int idx = blockIdx.x * DD + threadIdx.x;
    out[idx] = (part[idx] + part[BB * DD + idx]) +
               (part[2 * BB * DD + idx] + part[3 * BB * DD + idx]);
}

// ---------------- launch ---------------------------------------------------------
extern "C" void kernel_launch(void* const* d_in, const int* in_sizes, int n_in,
                              void* d_out, int out_size, void* d_ws, size_t ws_size,
                              hipStream_t stream) {
    (void)in_sizes; (void)n_in; (void)out_size; (void)ws_size;
    const float* x = (const float*)d_in[0];
    // d_in[1] = x_mask (unused), d_in[3] = f (unused)
    const int* q = (const int*)d_in[2];
    const float* R = (const float*)d_in[4];
    float* out = (float*)d_out;

    char* ws = (char*)d_ws;
    unsigned short* xbf  = (unsigned short*)(ws);                  // 512 KB
    unsigned short* xbfT = (unsigned short*)(ws + (512u << 10));   // 512 KB
    unsigned short* P    = (unsigned short*)(ws + (1024u << 10));  // 2 MB
    float*          part = (float*)(ws + (3072u << 10));           // 4 MB (z=4)

    cvt_kernel<<<dim3(16, 4), 256, 0, stream>>>(x, xbf, xbfT);
    attn_kernel<<<dim3(512), 128, 0, stream>>>(x, q, R, xbf, P);
    out_partial<<<dim3(4, 16, 4), 256, 0, stream>>>(P, xbfT, part);
    out_reduce<<<dim3(BB), 256, 0, stream>>>(part, out);
}

// Round 4
// 66.477 us; speedup vs baseline: 1.7870x; 1.1692x over previous
//
#include <hip/hip_runtime.h>
#include <hip/hip_bf16.h>

#define BB 1024
#define DD 256
#define NREL 42

typedef __attribute__((ext_vector_type(8))) short short8_t;
typedef __attribute__((ext_vector_type(4))) short short4_t;
typedef __attribute__((ext_vector_type(4))) float f32x4;
typedef __attribute__((ext_vector_type(4))) int   i32x4;

__device__ __forceinline__ unsigned short bf16_of(float f) {
    // round-to-nearest-even f32 -> bf16 (inputs are finite normals)
    unsigned u = __float_as_uint(f);
    return (unsigned short)((u + 0x7FFFu + ((u >> 16) & 1u)) >> 16);
}

__device__ __forceinline__ void gload_lds16(const unsigned short* g, unsigned short* l) {
    __builtin_amdgcn_global_load_lds(
        (const __attribute__((address_space(1))) unsigned int*)g,
        (__attribute__((address_space(3))) unsigned int*)l, 16, 0, 0);
}

// ---------------- K0: x -> bf16 row-major + LDS-tiled transpose -----------------
__global__ __launch_bounds__(256) void cvt_kernel(const float* __restrict__ x,
                                                  unsigned short* __restrict__ xbf,
                                                  unsigned short* __restrict__ xbfT) {
    __shared__ unsigned short t[64][72];
    const int bj = blockIdx.x * 64;
    const int bd = blockIdx.y * 64;
    const int tr = threadIdx.x >> 4;
    const int tc = threadIdx.x & 15;

    #pragma unroll
    for (int rr = 0; rr < 4; ++rr) {
        const int jl = rr * 16 + tr;
        const f32x4 v = *reinterpret_cast<const f32x4*>(&x[(bj + jl) * DD + bd + tc * 4]);
        short4_t h;
        #pragma unroll
        for (int e = 0; e < 4; ++e) h[e] = (short)bf16_of(v[e]);
        *reinterpret_cast<short4_t*>(&xbf[(bj + jl) * DD + bd + tc * 4]) = h;
        *reinterpret_cast<short4_t*>(&t[jl][tc * 4]) = h;
    }
    __syncthreads();
    #pragma unroll
    for (int rr = 0; rr < 4; ++rr) {
        const int dl = rr * 16 + tr;
        short4_t h;
        #pragma unroll
        for (int e = 0; e < 4; ++e) h[e] = (short)t[tc * 4 + e][dl];
        *reinterpret_cast<short4_t*>(&xbfT[(bd + dl) * BB + bj + tc * 4]) = h;
    }
}

// ---------------- K1 (fused): logits GEMM + gather + softmax -> normalized P ----
// 256 blocks x 256 thr. Wave w owns row i = 4*blk + w: A_i (48x256) in VGPRs,
// computes S_i = A_i @ B^T for all 1024 j in 32-j tiles. B tiles double-buffered
// in LDS (XOR-swizzled, global_load_lds width 16), each wave stages its own 4
// chunks for tile t+1 before computing tile t. Epilogue gathers row q[i,j];
// per-wave softmax normalizes and writes P.
__global__ __launch_bounds__(256, 1) void attn_kernel(const float* __restrict__ x,
                                                      const int* __restrict__ q,
                                                      const float* __restrict__ R,
                                                      const unsigned short* __restrict__ xbf,
                                                      unsigned short* __restrict__ P) {
    __shared__ unsigned short Bt[2][16384];     // 2 x (32 j x 256 d) bf16, swizzled
    __shared__ float s_attn[4][BB];             // per-wave logit row
    __shared__ unsigned short s_qs[4][BB];      // per-wave q row (values < 42)

    const int tid  = threadIdx.x;
    const int w    = tid >> 6;
    const int lane = tid & 63;
    const int lcol = lane & 15;
    const int g    = lane >> 4;
    const int lk8  = g * 8;
    const int l5   = lane >> 5, l31 = lane & 31;
    const int i    = blockIdx.x * 4 + w;

    // --- stage tile 0 (my 4 chunks; 1 chunk = 2 rows of 512 B) ---
    #pragma unroll
    for (int c0 = 0; c0 < 4; ++c0) {
        const int c = w * 4 + c0;
        const int row = c * 2 + l5;
        const int scol = ((l31 * 16) ^ ((row & 7) << 4)) >> 1;   // pre-swizzled source
        gload_lds16(&xbf[row * DD + scol], &Bt[0][c * 512]);
    }

    // --- q row -> LDS (u16) ---
    #pragma unroll
    for (int kk = 0; kk < 4; ++kk) {
        const i32x4 qv = *reinterpret_cast<const i32x4*>(&q[i * BB + kk * 256 + lane * 4]);
        short4_t qs;
        qs[0] = (short)qv[0]; qs[1] = (short)qv[1];
        qs[2] = (short)qv[2]; qs[3] = (short)qv[3];
        *reinterpret_cast<short4_t*>(&s_qs[w][kk * 256 + lane * 4]) = qs;
    }

    // --- A_i fragments in registers: afrag[mt*8+ks] = bf16(R[k][d]*x[i][d]) ---
    short8_t afrag[24];
    #pragma unroll
    for (int ks = 0; ks < 8; ++ks) {
        const int d0 = ks * 32 + lk8;
        const f32x4 x0 = *reinterpret_cast<const f32x4*>(&x[i * DD + d0]);
        const f32x4 x1 = *reinterpret_cast<const f32x4*>(&x[i * DD + d0 + 4]);
        #pragma unroll
        for (int mt = 0; mt < 3; ++mt) {
            const int k = mt * 16 + lcol;
            short8_t v = (short8_t)0;
            if (k < NREL) {
                const f32x4 r0 = *reinterpret_cast<const f32x4*>(&R[k * DD + d0]);
                const f32x4 r1 = *reinterpret_cast<const f32x4*>(&R[k * DD + d0 + 4]);
                #pragma unroll
                for (int e = 0; e < 4; ++e) {
                    v[e]     = (short)bf16_of(r0[e] * x0[e]);
                    v[e + 4] = (short)bf16_of(r1[e] * x1[e]);
                }
            }
            afrag[mt * 8 + ks] = v;
        }
    }

    __syncthreads();

    const int gsw = (g * 16) ^ ((lcol & 7) << 4);   // swizzled in-row byte base

    for (int t = 0; t < 32; ++t) {
        // issue next-tile staging BEFORE compute (L2 latency hides under MFMA)
        if (t < 31) {
            unsigned short* nxt = Bt[(t + 1) & 1];
            const unsigned short* src = &xbf[(t + 1) * 32 * DD];
            #pragma unroll
            for (int c0 = 0; c0 < 4; ++c0) {
                const int c = w * 4 + c0;
                const int row = c * 2 + l5;
                const int scol = ((l31 * 16) ^ ((row & 7) << 4)) >> 1;
                gload_lds16(&src[row * DD + scol], &nxt[c * 512]);
            }
        }

        const char* cur = (const char*)Bt[t & 1];
        f32x4 acc[3][2];
        #pragma unroll
        for (int mt = 0; mt < 3; ++mt) {
            acc[mt][0] = (f32x4)0.0f; acc[mt][1] = (f32x4)0.0f;
        }

        #pragma unroll
        for (int ks = 0; ks < 8; ++ks) {
            #pragma unroll
            for (int nt = 0; nt < 2; ++nt) {
                const int off = (nt * 16 + lcol) * 512 + ((ks * 64) ^ gsw);
                const short8_t b = *reinterpret_cast<const short8_t*>(cur + off);
                #pragma unroll
                for (int mt = 0; mt < 3; ++mt)
                    acc[mt][nt] = __builtin_amdgcn_mfma_f32_16x16x32_bf16(
                        afrag[mt * 8 + ks], b, acc[mt][nt], 0, 0, 0);
            }
        }

        // Epilogue: exactly one lane per j writes S[q[i,j], j] into the logit row.
        #pragma unroll
        for (int nt = 0; nt < 2; ++nt) {
            const int jl = t * 32 + nt * 16 + lcol;
            const int qv = (int)s_qs[w][jl];
            if (((qv >> 2) & 3) == g) {
                const int mt = qv >> 4;                       // 0..2 (qv < 42)
                const f32x4 av = (mt == 0) ? acc[0][nt] : (mt == 1) ? acc[1][nt] : acc[2][nt];
                const float v = (qv & 2) ? ((qv & 1) ? av[3] : av[2])
                                         : ((qv & 1) ? av[1] : av[0]);
                s_attn[w][jl] = v;
            }
        }

        asm volatile("s_waitcnt vmcnt(0)" ::: "memory");   // my 4 staged loads (free by now)
        __syncthreads();
    }

    // --- per-wave softmax over own row; write normalized P (bf16) ---
    f32x4 v4[4];
    #pragma unroll
    for (int kk = 0; kk < 4; ++kk)
        v4[kk] = *reinterpret_cast<const f32x4*>(&s_attn[w][kk * 256 + lane * 4]);

    float m = -1e30f;
    #pragma unroll
    for (int kk = 0; kk < 4; ++kk)
        m = fmaxf(m, fmaxf(fmaxf(v4[kk][0], v4[kk][1]), fmaxf(v4[kk][2], v4[kk][3])));
    #pragma unroll
    for (int off = 1; off < 64; off <<= 1) m = fmaxf(m, __shfl_xor(m, off));

    float e[16];
    float ssum = 0.f;
    #pragma unroll
    for (int kk = 0; kk < 4; ++kk)
        #pragma unroll
        for (int ee = 0; ee < 4; ++ee) {
            const float t2 = __expf(v4[kk][ee] - m);
            e[kk * 4 + ee] = t2;
            ssum += t2;
        }
    #pragma unroll
    for (int off = 1; off < 64; off <<= 1) ssum += __shfl_xor(ssum, off);
    const float inv = 1.0f / ssum;

    #pragma unroll
    for (int kk = 0; kk < 4; ++kk) {
        short4_t p;
        #pragma unroll
        for (int ee = 0; ee < 4; ++ee) p[ee] = (short)bf16_of(e[kk * 4 + ee] * inv);
        *reinterpret_cast<short4_t*>(&P[i * BB + kk * 256 + lane * 4]) = p;
    }
}

// ---------------- K3a: partial out GEMM, split-K z=4 -----------------------------
__global__ __launch_bounds__(256) void out_partial(const unsigned short* __restrict__ P,
                                                   const unsigned short* __restrict__ xbfT,
                                                   float* __restrict__ part) {
    const int tid = threadIdx.x;
    const int wave = tid >> 6, lane = tid & 63;
    const int lcol = lane & 15;
    const int lk8  = (lane >> 4) * 8;
    const int i0 = blockIdx.y * 64 + wave * 16;
    const int d0 = blockIdx.x * 64;
    const int k0 = blockIdx.z * 256;

    f32x4 acc[4];
    #pragma unroll
    for (int nt = 0; nt < 4; ++nt) acc[nt] = (f32x4)0.0f;

    #pragma unroll
    for (int ks = 0; ks < 8; ++ks) {
        const short8_t a = *reinterpret_cast<const short8_t*>(
            &P[(i0 + lcol) * BB + k0 + ks * 32 + lk8]);
        #pragma unroll
        for (int nt = 0; nt < 4; ++nt) {
            const short8_t b = *reinterpret_cast<const short8_t*>(
                &xbfT[(d0 + nt * 16 + lcol) * BB + k0 + ks * 32 + lk8]);
            acc[nt] = __builtin_amdgcn_mfma_f32_16x16x32_bf16(a, b, acc[nt], 0, 0, 0);
        }
    }

    const int rbase = (lane >> 4) * 4;
    float* pz = part + (size_t)blockIdx.z * BB * DD;
    #pragma unroll
    for (int r = 0; r < 4; ++r)
        #pragma unroll
        for (int nt = 0; nt < 4; ++nt)
            pz[(i0 + rbase + r) * DD + d0 + nt * 16 + lcol] = acc[nt][r];
}

// ---------------- K3b: out = sum_z part[z] (P already normalized) ---------------
__global__ __launch_bounds__(256) void out_reduce(const float* __restrict__ part,
                                                  float* __restrict__ out) {
    const int idx = blockIdx.x * DD + threadIdx.x;
    out[idx] = (part[idx] + part[BB * DD + idx]) +
               (part[2 * BB * DD + idx] + part[3 * BB * DD + idx]);
}

// ---------------- launch ---------------------------------------------------------
extern "C" void kernel_launch(void* const* d_in, const int* in_sizes, int n_in,
                              void* d_out, int out_size, void* d_ws, size_t ws_size,
                              hipStream_t stream) {
    (void)in_sizes; (void)n_in; (void)out_size; (void)ws_size;
    const float* x = (const float*)d_in[0];
    // d_in[1] = x_mask (unused), d_in[3] = f (unused)
    const int* q = (const int*)d_in[2];
    const float* R = (const float*)d_in[4];
    float* out = (float*)d_out;

    char* ws = (char*)d_ws;
    unsigned short* xbf  = (unsigned short*)(ws);                  // 512 KB
    unsigned short* xbfT = (unsigned short*)(ws + (512u << 10));   // 512 KB
    unsigned short* P    = (unsigned short*)(ws + (1024u << 10));  // 2 MB
    float*          part = (float*)(ws + (3072u << 10));           // 4 MB (z=4)

    cvt_kernel<<<dim3(16, 4), 256, 0, stream>>>(x, xbf, xbfT);
    attn_kernel<<<dim3(256), 256, 0, stream>>>(x, q, R, xbf, P);
    out_partial<<<dim3(4, 16, 4), 256, 0, stream>>>(P, xbfT, part);
    out_reduce<<<dim3(BB), 256, 0, stream>>>(part, out);
}